// Round 4
// baseline (2047.307 us; speedup 1.0000x reference)
//
#include <hip/hip_runtime.h>
#include <math.h>

// GraphODE (GCN + RK4 ODE block) on MI355X, fp32.
// Round 4: float4 gathers -- one wave covers 4 edges x 16 float4-lanes per
// VMEM instruction (4x fewer gather instructions than round 3), slot-partial
// sums reduced via shfl_xor(16/32). GroupNorm pairs are lane-local in this
// layout. k_final uses a 64-stride zero-padded s2 for the same gather shape.

constexpr int kN = 100000;   // nodes
constexpr int kE = 1600000;  // edges
constexpr int kNPAD = 100352; // 98*1024
constexpr float kDT = 0.25f;
constexpr float kEPS = 1e-5f;

__device__ __forceinline__ float4 ld4(const float* p) { return *(const float4*)p; }
__device__ __forceinline__ void st4(float* p, float4 v) { *(float4*)p = v; }

// ---------------- CSR build ----------------
__global__ void k_zero(int* cnt) {
  int i = blockIdx.x * 256 + threadIdx.x;
  if (i < kN) cnt[i] = 0;
}

__global__ void k_hist(const int* __restrict__ tgt, int* __restrict__ cnt) {
  int e = blockIdx.x * 256 + threadIdx.x;
  if (e < kE) atomicAdd(&cnt[tgt[e]], 1);
}

__global__ __launch_bounds__(256) void k_scan_a(const int* __restrict__ cnt,
                                                int* __restrict__ ptr,
                                                int* __restrict__ bsum) {
  int tid = threadIdx.x;
  int base = blockIdx.x * 1024;
  int i0 = base + tid * 4;
  int v[4];
#pragma unroll
  for (int t = 0; t < 4; ++t) v[t] = (i0 + t < kN) ? cnt[i0 + t] : 0;
  int ts = v[0] + v[1] + v[2] + v[3];
  int lane = tid & 63;
  int x = ts;
#pragma unroll
  for (int off = 1; off < 64; off <<= 1) {
    int y = __shfl_up(x, off);
    if (lane >= off) x += y;
  }
  __shared__ int wsum[4];
  if (lane == 63) wsum[tid >> 6] = x;
  __syncthreads();
  int woff = 0;
#pragma unroll
  for (int w = 0; w < 4; ++w)
    if (w < (tid >> 6)) woff += wsum[w];
  int o = woff + (x - ts);  // exclusive within block
#pragma unroll
  for (int t = 0; t < 4; ++t) {
    if (i0 + t < kN) ptr[i0 + t] = o;
    o += v[t];
  }
  if (tid == 255) bsum[blockIdx.x] = woff + x;  // block total
}

__global__ void k_scan_b(int* bsum, int nb) {
  int lane = threadIdx.x;  // blockDim = 64
  int carry = 0;
  for (int b = 0; b < nb; b += 64) {
    int i = b + lane;
    int v = (i < nb) ? bsum[i] : 0;
    int x = v;
#pragma unroll
    for (int off = 1; off < 64; off <<= 1) {
      int y = __shfl_up(x, off);
      if (lane >= off) x += y;
    }
    if (i < nb) bsum[i] = carry + x - v;  // exclusive
    carry += __shfl(x, 63);
  }
}

__global__ void k_scan_c(const int* __restrict__ bsum, int* __restrict__ ptr,
                         int* __restrict__ runp) {
  int i = blockIdx.x * 256 + threadIdx.x;
  if (i < kN) {
    int v = ptr[i] + bsum[i >> 10];
    ptr[i] = v;
    runp[i] = v;
  }
  if (i == 0) ptr[kN] = kE;
}

__global__ void k_scatter(const int* __restrict__ src, const int* __restrict__ tgt,
                          const float* __restrict__ w, int* __restrict__ runp,
                          float2* __restrict__ meta) {
  int e = blockIdx.x * 256 + threadIdx.x;
  if (e < kE) {
    int t = tgt[e];
    int pos = atomicAdd(&runp[t], 1);
    meta[pos] = make_float2(__int_as_float(src[e]), w[e]);
  }
}

// ------------- float4 gather: 4 edges per VMEM instruction -----------------
// lane = (slot = lane>>4, fc = lane&15). One chunk covers edges e..e+3:
// lane loads S4[src[e+slot]*16 + fc] (16B) and FMAs with w[e+slot].
// Slot partials are reduced by shfl_xor(16), shfl_xor(32) at the end.
template <bool DSUM>
__device__ __forceinline__ void g_chunk4(const float2* __restrict__ meta,
                                         const float4* __restrict__ S4,
                                         int e, int rem, int slot, int fc,
                                         float4& acc, float& ds) {
  float2 m0 = meta[e + 0], m1 = meta[e + 1], m2 = meta[e + 2], m3 = meta[e + 3];
  int idx = slot == 1 ? __float_as_int(m1.x)
          : slot == 2 ? __float_as_int(m2.x)
          : slot == 3 ? __float_as_int(m3.x)
                      : __float_as_int(m0.x);
  float w = slot == 1 ? m1.y : slot == 2 ? m2.y : slot == 3 ? m3.y : m0.y;
  if (rem < 4) {  // masked tail (meta reads past e1 stay inside the ws buffer)
    bool ok = slot < rem;
    idx = ok ? idx : 0;
    w = ok ? w : 0.f;
  }
  float4 v = S4[idx * 16 + fc];
  acc.x += w * v.x; acc.y += w * v.y; acc.z += w * v.z; acc.w += w * v.w;
  if (DSUM) ds += w;
}

template <bool DSUM>
__device__ __forceinline__ float4 gather_row4(const float2* __restrict__ meta,
                                              const float4* __restrict__ S4,
                                              int e0, int e1, int slot, int fc,
                                              float& dsum) {
  float4 acc = make_float4(0.f, 0.f, 0.f, 0.f);
  float ds = 0.f;
  int e = e0;
  for (; e + 16 <= e1; e += 16) {  // 4 independent dwordx4 gathers in flight
    g_chunk4<DSUM>(meta, S4, e + 0, 4, slot, fc, acc, ds);
    g_chunk4<DSUM>(meta, S4, e + 4, 4, slot, fc, acc, ds);
    g_chunk4<DSUM>(meta, S4, e + 8, 4, slot, fc, acc, ds);
    g_chunk4<DSUM>(meta, S4, e + 12, 4, slot, fc, acc, ds);
  }
  if (e + 8 <= e1) {
    g_chunk4<DSUM>(meta, S4, e + 0, 4, slot, fc, acc, ds);
    g_chunk4<DSUM>(meta, S4, e + 4, 4, slot, fc, acc, ds);
    e += 8;
  }
  if (e + 4 <= e1) {
    g_chunk4<DSUM>(meta, S4, e, 4, slot, fc, acc, ds);
    e += 4;
  }
  if (e < e1) g_chunk4<DSUM>(meta, S4, e, e1 - e, slot, fc, acc, ds);
  acc.x += __shfl_xor(acc.x, 16); acc.y += __shfl_xor(acc.y, 16);
  acc.z += __shfl_xor(acc.z, 16); acc.w += __shfl_xor(acc.w, 16);
  acc.x += __shfl_xor(acc.x, 32); acc.y += __shfl_xor(acc.y, 32);
  acc.z += __shfl_xor(acc.z, 32); acc.w += __shfl_xor(acc.w, 32);
  if (DSUM) {
    ds += __shfl_xor(ds, 16);
    ds += __shfl_xor(ds, 32);
    dsum = ds;
  }
  return acc;
}

// ---------------- SpMM: one node per wave ----------------
// LAYER0=1: h = relu(A@s), hn = gn(h), degw = row-sums.  LAYER0=0: z = A@hn.
template <int LAYER0>
__global__ __launch_bounds__(256) void k_spmm(
    const int* __restrict__ ptr, const float2* __restrict__ meta,
    const float4* __restrict__ S4, float4* __restrict__ z4,
    float* __restrict__ h, float* __restrict__ hn,
    const float* __restrict__ gn_w, const float* __restrict__ gn_b,
    float* __restrict__ degw) {
  int wid = (blockIdx.x * 256 + threadIdx.x) >> 6;
  int lane = threadIdx.x & 63;
  if (wid >= kN) return;
  int slot = lane >> 4, fc = lane & 15;
  int e0 = __builtin_amdgcn_readfirstlane(ptr[wid]);
  int e1 = __builtin_amdgcn_readfirstlane(ptr[wid + 1]);
  float dsum = 0.f;
  float4 acc = gather_row4<LAYER0 != 0>(meta, S4, e0, e1, slot, fc, dsum);
  if (LAYER0) {
    float4 hv = make_float4(fmaxf(acc.x, 0.f), fmaxf(acc.y, 0.f),
                            fmaxf(acc.z, 0.f), fmaxf(acc.w, 0.f));
    // GroupNorm group-size 2: pairs (x,y), (z,w) are lane-local
    float dx = 0.5f * (hv.x - hv.y);
    float rx = dx * rsqrtf(dx * dx + kEPS);
    float dz = 0.5f * (hv.z - hv.w);
    float rz = dz * rsqrtf(dz * dz + kEPS);
    float4 gw = ld4(gn_w + fc * 4);
    float4 gb = ld4(gn_b + fc * 4);
    float4 o = make_float4(rx * gw.x + gb.x, -rx * gw.y + gb.y,
                           rz * gw.z + gb.z, -rz * gw.w + gb.w);
    if (slot == 0) {
      st4(h + wid * 64 + fc * 4, hv);
      st4(hn + wid * 64 + fc * 4, o);
      if (fc == 0) degw[wid] = dsum;
    }
  } else {
    if (slot == 0) z4[wid * 16 + fc] = acc;
  }
}

// ---------------- tiled stage GEMM + RK4 epilogue (proven) ---------
__global__ __launch_bounds__(256) void k_gemm_stage(
    const float* __restrict__ z, const float* __restrict__ W1,
    const float* __restrict__ b1, const float* __restrict__ gn_w,
    const float* __restrict__ gn_b, const float* __restrict__ degw,
    float* __restrict__ h, float* __restrict__ kacc, float* __restrict__ hn,
    float t_s, float a_next, float coef, int init_acc, int is_stage3) {
  constexpr int NT = 128, ST = NT + 4, K = 64;
  __shared__ float Wl[K * 64];
  __shared__ float Zt[K * ST];
  const int tid = threadIdx.x;
  const int base = blockIdx.x * NT;
  const float* Wr = W1 + 64;  // rows 1..64 of W1
  for (int i = tid; i < K * 64; i += 256) Wl[i] = Wr[i];
  for (int idx = tid; idx < (K / 4) * NT; idx += 256) {
    int node = idx & (NT - 1);
    int k4 = idx >> 7;
    int g = base + node;
    float4 v = make_float4(0.f, 0.f, 0.f, 0.f);
    if (g < kN) v = ld4(z + (long)g * 64 + k4 * 4);
    int kk = k4 * 4;
    Zt[(kk + 0) * ST + node] = v.x;
    Zt[(kk + 1) * ST + node] = v.y;
    Zt[(kk + 2) * ST + node] = v.z;
    Zt[(kk + 3) * ST + node] = v.w;
  }
  __syncthreads();
  const int c0 = (tid & 15) * 4;
  const int n0 = (tid >> 4) * 8;
  float acc[8][4] = {};
#pragma unroll 8
  for (int j = 0; j < K; ++j) {
    float4 wv = ld4(Wl + j * 64 + c0);
    float4 za = ld4(Zt + j * ST + n0);
    float4 zb = ld4(Zt + j * ST + n0 + 4);
    float zv[8] = {za.x, za.y, za.z, za.w, zb.x, zb.y, zb.z, zb.w};
#pragma unroll
    for (int i = 0; i < 8; ++i) {
      acc[i][0] += zv[i] * wv.x;
      acc[i][1] += zv[i] * wv.y;
      acc[i][2] += zv[i] * wv.z;
      acc[i][3] += zv[i] * wv.w;
    }
  }
  float4 w0r = ld4(W1 + c0);
  float4 b1v = ld4(b1 + c0);
  float4 bias = make_float4(t_s * w0r.x + b1v.x, t_s * w0r.y + b1v.y,
                            t_s * w0r.z + b1v.z, t_s * w0r.w + b1v.w);
  float4 gw = ld4(gn_w + c0);
  float4 gb = ld4(gn_b + c0);
  const float c6 = kDT / 6.f;
#pragma unroll
  for (int i = 0; i < 8; ++i) {
    int g = base + n0 + i;
    if (g >= kN) break;
    float dg = degw[g];
    float4 kv = make_float4(fmaxf(acc[i][0] + dg * bias.x, 0.f),
                            fmaxf(acc[i][1] + dg * bias.y, 0.f),
                            fmaxf(acc[i][2] + dg * bias.z, 0.f),
                            fmaxf(acc[i][3] + dg * bias.w, 0.f));
    long o64 = (long)g * 64 + c0;
    float4 ka;
    if (init_acc) {
      ka = kv;
    } else {
      ka = ld4(kacc + o64);
      ka.x += coef * kv.x; ka.y += coef * kv.y;
      ka.z += coef * kv.z; ka.w += coef * kv.w;
    }
    if (!is_stage3) st4(kacc + o64, ka);
    float4 hv = ld4(h + o64);
    float4 y;
    if (is_stage3) {
      y = make_float4(hv.x + c6 * ka.x, hv.y + c6 * ka.y,
                      hv.z + c6 * ka.z, hv.w + c6 * ka.w);
      st4(h + o64, y);
    } else {
      y = make_float4(hv.x + a_next * kv.x, hv.y + a_next * kv.y,
                      hv.z + a_next * kv.z, hv.w + a_next * kv.w);
    }
    float dx = 0.5f * (y.x - y.y);
    float rx = dx * rsqrtf(dx * dx + kEPS);
    float dz = 0.5f * (y.z - y.w);
    float rz = dz * rsqrtf(dz * dz + kEPS);
    float4 o = make_float4(rx * gw.x + gb.x, -rx * gw.y + gb.y,
                           rz * gw.z + gb.z, -rz * gw.w + gb.w);
    st4(hn + o64, o);
  }
}

// -------- final: float4 gather over 64-stride padded s2 + log_softmax ------
__global__ __launch_bounds__(256) void k_final(const int* __restrict__ ptr,
                                               const float2* __restrict__ meta,
                                               const float4* __restrict__ s2,
                                               float* __restrict__ out) {
  int wid = (blockIdx.x * 256 + threadIdx.x) >> 6;
  int lane = threadIdx.x & 63;
  if (wid >= kN) return;
  int slot = lane >> 4, fc = lane & 15;
  int e0 = __builtin_amdgcn_readfirstlane(ptr[wid]);
  int e1 = __builtin_amdgcn_readfirstlane(ptr[wid + 1]);
  float dum;
  float4 a = gather_row4<false>(meta, s2, e0, e1, slot, fc, dum);
  bool valid = fc < 10;  // 40 logits = 10 float4 lanes
  float m = valid ? fmaxf(fmaxf(a.x, a.y), fmaxf(a.z, a.w)) : -INFINITY;
#pragma unroll
  for (int off = 1; off < 16; off <<= 1) m = fmaxf(m, __shfl_xor(m, off));
  float s = valid ? expf(a.x - m) + expf(a.y - m) + expf(a.z - m) + expf(a.w - m)
                  : 0.f;
#pragma unroll
  for (int off = 1; off < 16; off <<= 1) s += __shfl_xor(s, off);
  float lse = logf(s) + m;
  if (slot == 0 && valid)
    st4(out + (long)wid * 40 + fc * 4,
        make_float4(a.x - lse, a.y - lse, a.z - lse, a.w - lse));
}

// ------- plain GEMM: out[:, :64@OST] = beta*out + in[:, :64]@W + bias ------
// Weight cols >= NCOL are zero-filled so pad columns of out get zeros.
template <int NCOL, int OST>
__global__ __launch_bounds__(256) void k_gemm64(const float* __restrict__ in,
                                                int in_stride,
                                                const float* __restrict__ W,
                                                const float* __restrict__ bias,
                                                float* __restrict__ out, int beta) {
  constexpr int NT = 128, ST = NT + 4, K = 64;
  __shared__ float Wl[K * 64];
  __shared__ float Zt[K * ST];
  const int tid = threadIdx.x;
  const int base = blockIdx.x * NT;
  for (int i = tid; i < K * 64; i += 256) {
    int j = i >> 6, c = i & 63;
    Wl[i] = (c < NCOL) ? W[j * NCOL + c] : 0.f;
  }
  for (int idx = tid; idx < (K / 4) * NT; idx += 256) {
    int node = idx & (NT - 1);
    int k4 = idx >> 7;
    int g = base + node;
    float4 v = make_float4(0.f, 0.f, 0.f, 0.f);
    if (g < kN) v = ld4(in + (long)g * in_stride + k4 * 4);
    int kk = k4 * 4;
    Zt[(kk + 0) * ST + node] = v.x;
    Zt[(kk + 1) * ST + node] = v.y;
    Zt[(kk + 2) * ST + node] = v.z;
    Zt[(kk + 3) * ST + node] = v.w;
  }
  __syncthreads();
  const int c0 = (tid & 15) * 4;
  const int n0 = (tid >> 4) * 8;
  float acc[8][4] = {};
#pragma unroll 8
  for (int j = 0; j < K; ++j) {
    float4 wv = ld4(Wl + j * 64 + c0);
    float4 za = ld4(Zt + j * ST + n0);
    float4 zb = ld4(Zt + j * ST + n0 + 4);
    float zv[8] = {za.x, za.y, za.z, za.w, zb.x, zb.y, zb.z, zb.w};
#pragma unroll
    for (int i = 0; i < 8; ++i) {
      acc[i][0] += zv[i] * wv.x;
      acc[i][1] += zv[i] * wv.y;
      acc[i][2] += zv[i] * wv.z;
      acc[i][3] += zv[i] * wv.w;
    }
  }
  float4 bv = make_float4(0.f, 0.f, 0.f, 0.f);
  if (bias && c0 < NCOL) bv = ld4(bias + c0);
#pragma unroll
  for (int i = 0; i < 8; ++i) {
    int g = base + n0 + i;
    if (g >= kN) break;
    float* op = out + (long)g * OST + c0;
    float4 o = make_float4(acc[i][0] + bv.x, acc[i][1] + bv.y,
                           acc[i][2] + bv.z, acc[i][3] + bv.w);
    if (beta) {
      float4 p = ld4(op);
      o.x += p.x; o.y += p.y; o.z += p.z; o.w += p.w;
    }
    st4(op, o);
  }
}

// ---------------- launch ----------------
extern "C" void kernel_launch(void* const* d_in, const int* in_sizes, int n_in,
                              void* d_out, int out_size, void* d_ws, size_t ws_size,
                              hipStream_t stream) {
  const float* x = (const float*)d_in[0];
  const int* src = (const int*)d_in[1];
  const int* tgt = (const int*)d_in[2];
  const float* mw = (const float*)d_in[3];
  const float* W0 = (const float*)d_in[4];
  const float* b0 = (const float*)d_in[5];
  const float* gnw = (const float*)d_in[6];
  const float* gnb = (const float*)d_in[7];
  const float* W1 = (const float*)d_in[8];
  const float* b1 = (const float*)d_in[9];
  const float* W2 = (const float*)d_in[10];
  const float* b2 = (const float*)d_in[11];
  float* out = (float*)d_out;

  // workspace carve-up (16B aligned regions)
  int* cnt_run = (int*)d_ws;                 // kNPAD ints
  int* csr_ptr = cnt_run + kNPAD;            // kNPAD ints (need kN+1)
  int* bsum = csr_ptr + kNPAD;               // 128 ints
  float2* meta = (float2*)(bsum + 128);      // kE float2 (+ slack after)
  float* degw = (float*)(meta + kE);         // kNPAD floats (also meta OOB pad)
  float* h = degw + kNPAD;                   // kN*64
  float* hn = h + (long)kN * 64;
  float* z = hn + (long)kN * 64;
  float* kacc = z + (long)kN * 64;

  // CSR build
  k_zero<<<391, 256, 0, stream>>>(cnt_run);
  k_hist<<<6250, 256, 0, stream>>>(tgt, cnt_run);
  k_scan_a<<<98, 256, 0, stream>>>(cnt_run, csr_ptr, bsum);
  k_scan_b<<<1, 64, 0, stream>>>(bsum, 98);
  k_scan_c<<<391, 256, 0, stream>>>(bsum, csr_ptr, cnt_run);
  k_scatter<<<6250, 256, 0, stream>>>(src, tgt, mw, cnt_run, meta);

  // layer 0: z = x@W0 + b0 (two K=64 passes), then h/hn/degw
  k_gemm64<64, 64><<<782, 256, 0, stream>>>(x, 128, W0, nullptr, z, 0);
  k_gemm64<64, 64><<<782, 256, 0, stream>>>(x + 64, 128, W0 + 64 * 64, b0, z, 1);
  k_spmm<1><<<25000, 256, 0, stream>>>(csr_ptr, meta, (const float4*)z, nullptr,
                                       h, hn, gnw, gnb, degw);

  // RK4 over t = 0, .25, .5, .75
  for (int step = 0; step < 4; ++step) {
    float t = step * kDT;
    const float ts[4] = {t, t + 0.5f * kDT, t + 0.5f * kDT, t + kDT};
    const float an[4] = {0.5f * kDT, 0.5f * kDT, kDT, 0.f};
    const float cf[4] = {1.f, 2.f, 2.f, 1.f};
    for (int s = 0; s < 4; ++s) {
      k_spmm<0><<<25000, 256, 0, stream>>>(csr_ptr, meta, (const float4*)hn,
                                           (float4*)z, nullptr, nullptr, nullptr,
                                           nullptr, nullptr);
      k_gemm_stage<<<782, 256, 0, stream>>>(z, W1, b1, gnw, gnb, degw, h, kacc, hn,
                                            ts[s], an[s], cf[s],
                                            (s == 0) ? 1 : 0, (s == 3) ? 1 : 0);
    }
  }

  // final layer: s2 = h@W2 + b2 into 64-stride padded buffer (cols>=40 zero)
  k_gemm64<40, 64><<<782, 256, 0, stream>>>(h, 64, W2, b2, z, 0);
  k_final<<<25000, 256, 0, stream>>>(csr_ptr, meta, (const float4*)z, out);
}

// Round 5
// 1830.499 us; speedup vs baseline: 1.1184x; 1.1184x over previous
//
#include <hip/hip_runtime.h>
#include <hip/hip_fp16.h>
#include <math.h>

// GraphODE (GCN + RK4 ODE block) on MI355X.
// Round 5: ODE-stage gathers read hn stored as fp16 (bounded groupnorm
// output) -> halves the ~410 MB/pass L3 gather traffic that round-4 showed
// to be the bound (instruction-count change was neutral). Everything else
// (h, kacc, z, logits, layer-0, final) stays fp32.

constexpr int kN = 100000;   // nodes
constexpr int kE = 1600000;  // edges
constexpr int kNPAD = 100352; // 98*1024
constexpr float kDT = 0.25f;
constexpr float kEPS = 1e-5f;

__device__ __forceinline__ float4 ld4(const float* p) { return *(const float4*)p; }
__device__ __forceinline__ void st4(float* p, float4 v) { *(float4*)p = v; }

// ---------------- CSR build ----------------
__global__ void k_zero(int* cnt) {
  int i = blockIdx.x * 256 + threadIdx.x;
  if (i < kN) cnt[i] = 0;
}

__global__ void k_hist(const int* __restrict__ tgt, int* __restrict__ cnt) {
  int e = blockIdx.x * 256 + threadIdx.x;
  if (e < kE) atomicAdd(&cnt[tgt[e]], 1);
}

__global__ __launch_bounds__(256) void k_scan_a(const int* __restrict__ cnt,
                                                int* __restrict__ ptr,
                                                int* __restrict__ bsum) {
  int tid = threadIdx.x;
  int base = blockIdx.x * 1024;
  int i0 = base + tid * 4;
  int v[4];
#pragma unroll
  for (int t = 0; t < 4; ++t) v[t] = (i0 + t < kN) ? cnt[i0 + t] : 0;
  int ts = v[0] + v[1] + v[2] + v[3];
  int lane = tid & 63;
  int x = ts;
#pragma unroll
  for (int off = 1; off < 64; off <<= 1) {
    int y = __shfl_up(x, off);
    if (lane >= off) x += y;
  }
  __shared__ int wsum[4];
  if (lane == 63) wsum[tid >> 6] = x;
  __syncthreads();
  int woff = 0;
#pragma unroll
  for (int w = 0; w < 4; ++w)
    if (w < (tid >> 6)) woff += wsum[w];
  int o = woff + (x - ts);  // exclusive within block
#pragma unroll
  for (int t = 0; t < 4; ++t) {
    if (i0 + t < kN) ptr[i0 + t] = o;
    o += v[t];
  }
  if (tid == 255) bsum[blockIdx.x] = woff + x;  // block total
}

__global__ void k_scan_b(int* bsum, int nb) {
  int lane = threadIdx.x;  // blockDim = 64
  int carry = 0;
  for (int b = 0; b < nb; b += 64) {
    int i = b + lane;
    int v = (i < nb) ? bsum[i] : 0;
    int x = v;
#pragma unroll
    for (int off = 1; off < 64; off <<= 1) {
      int y = __shfl_up(x, off);
      if (lane >= off) x += y;
    }
    if (i < nb) bsum[i] = carry + x - v;  // exclusive
    carry += __shfl(x, 63);
  }
}

__global__ void k_scan_c(const int* __restrict__ bsum, int* __restrict__ ptr,
                         int* __restrict__ runp) {
  int i = blockIdx.x * 256 + threadIdx.x;
  if (i < kN) {
    int v = ptr[i] + bsum[i >> 10];
    ptr[i] = v;
    runp[i] = v;
  }
  if (i == 0) ptr[kN] = kE;
}

__global__ void k_scatter(const int* __restrict__ src, const int* __restrict__ tgt,
                          const float* __restrict__ w, int* __restrict__ runp,
                          float2* __restrict__ meta) {
  int e = blockIdx.x * 256 + threadIdx.x;
  if (e < kE) {
    int t = tgt[e];
    int pos = atomicAdd(&runp[t], 1);
    meta[pos] = make_float2(__int_as_float(src[e]), w[e]);
  }
}

// ---------------- fp32 float4 gather (layer-0 / final): 4 edges/instr ------
template <bool DSUM>
__device__ __forceinline__ void g_chunk4(const float2* __restrict__ meta,
                                         const float4* __restrict__ S4,
                                         int e, int rem, int slot, int fc,
                                         float4& acc, float& ds) {
  float2 m0 = meta[e + 0], m1 = meta[e + 1], m2 = meta[e + 2], m3 = meta[e + 3];
  int idx = slot == 1 ? __float_as_int(m1.x)
          : slot == 2 ? __float_as_int(m2.x)
          : slot == 3 ? __float_as_int(m3.x)
                      : __float_as_int(m0.x);
  float w = slot == 1 ? m1.y : slot == 2 ? m2.y : slot == 3 ? m3.y : m0.y;
  if (rem < 4) {
    bool ok = slot < rem;
    idx = ok ? idx : 0;
    w = ok ? w : 0.f;
  }
  float4 v = S4[idx * 16 + fc];
  acc.x += w * v.x; acc.y += w * v.y; acc.z += w * v.z; acc.w += w * v.w;
  if (DSUM) ds += w;
}

template <bool DSUM>
__device__ __forceinline__ float4 gather_row4(const float2* __restrict__ meta,
                                              const float4* __restrict__ S4,
                                              int e0, int e1, int slot, int fc,
                                              float& dsum) {
  float4 acc = make_float4(0.f, 0.f, 0.f, 0.f);
  float ds = 0.f;
  int e = e0;
  for (; e + 16 <= e1; e += 16) {
    g_chunk4<DSUM>(meta, S4, e + 0, 4, slot, fc, acc, ds);
    g_chunk4<DSUM>(meta, S4, e + 4, 4, slot, fc, acc, ds);
    g_chunk4<DSUM>(meta, S4, e + 8, 4, slot, fc, acc, ds);
    g_chunk4<DSUM>(meta, S4, e + 12, 4, slot, fc, acc, ds);
  }
  if (e + 8 <= e1) {
    g_chunk4<DSUM>(meta, S4, e + 0, 4, slot, fc, acc, ds);
    g_chunk4<DSUM>(meta, S4, e + 4, 4, slot, fc, acc, ds);
    e += 8;
  }
  if (e + 4 <= e1) {
    g_chunk4<DSUM>(meta, S4, e, 4, slot, fc, acc, ds);
    e += 4;
  }
  if (e < e1) g_chunk4<DSUM>(meta, S4, e, e1 - e, slot, fc, acc, ds);
  acc.x += __shfl_xor(acc.x, 16); acc.y += __shfl_xor(acc.y, 16);
  acc.z += __shfl_xor(acc.z, 16); acc.w += __shfl_xor(acc.w, 16);
  acc.x += __shfl_xor(acc.x, 32); acc.y += __shfl_xor(acc.y, 32);
  acc.z += __shfl_xor(acc.z, 32); acc.w += __shfl_xor(acc.w, 32);
  if (DSUM) {
    ds += __shfl_xor(ds, 16);
    ds += __shfl_xor(ds, 32);
    dsum = ds;
  }
  return acc;
}

// ---------------- fp16 gather (ODE stages): 4 edges/instr, 8B/lane --------
__device__ __forceinline__ void g_chunk4h(const float2* __restrict__ meta,
                                          const uint2* __restrict__ Sh,
                                          int e, int rem, int slot, int fc,
                                          float4& acc) {
  float2 m0 = meta[e + 0], m1 = meta[e + 1], m2 = meta[e + 2], m3 = meta[e + 3];
  int idx = slot == 1 ? __float_as_int(m1.x)
          : slot == 2 ? __float_as_int(m2.x)
          : slot == 3 ? __float_as_int(m3.x)
                      : __float_as_int(m0.x);
  float w = slot == 1 ? m1.y : slot == 2 ? m2.y : slot == 3 ? m3.y : m0.y;
  if (rem < 4) {
    bool ok = slot < rem;
    idx = ok ? idx : 0;
    w = ok ? w : 0.f;
  }
  uint2 u = Sh[idx * 16 + fc];  // 4 halfs
  float2 f01 = __half22float2(*(const __half2*)&u.x);
  float2 f23 = __half22float2(*(const __half2*)&u.y);
  acc.x += w * f01.x; acc.y += w * f01.y;
  acc.z += w * f23.x; acc.w += w * f23.y;
}

__device__ __forceinline__ float4 gather_row4h(const float2* __restrict__ meta,
                                               const uint2* __restrict__ Sh,
                                               int e0, int e1, int slot, int fc) {
  float4 acc = make_float4(0.f, 0.f, 0.f, 0.f);
  int e = e0;
  for (; e + 16 <= e1; e += 16) {
    g_chunk4h(meta, Sh, e + 0, 4, slot, fc, acc);
    g_chunk4h(meta, Sh, e + 4, 4, slot, fc, acc);
    g_chunk4h(meta, Sh, e + 8, 4, slot, fc, acc);
    g_chunk4h(meta, Sh, e + 12, 4, slot, fc, acc);
  }
  if (e + 8 <= e1) {
    g_chunk4h(meta, Sh, e + 0, 4, slot, fc, acc);
    g_chunk4h(meta, Sh, e + 4, 4, slot, fc, acc);
    e += 8;
  }
  if (e + 4 <= e1) {
    g_chunk4h(meta, Sh, e, 4, slot, fc, acc);
    e += 4;
  }
  if (e < e1) g_chunk4h(meta, Sh, e, e1 - e, slot, fc, acc);
  acc.x += __shfl_xor(acc.x, 16); acc.y += __shfl_xor(acc.y, 16);
  acc.z += __shfl_xor(acc.z, 16); acc.w += __shfl_xor(acc.w, 16);
  acc.x += __shfl_xor(acc.x, 32); acc.y += __shfl_xor(acc.y, 32);
  acc.z += __shfl_xor(acc.z, 32); acc.w += __shfl_xor(acc.w, 32);
  return acc;
}

__device__ __forceinline__ void st_half4(unsigned short* p, float4 v) {
  __half2 a = __floats2half2_rn(v.x, v.y);
  __half2 b = __floats2half2_rn(v.z, v.w);
  uint2 u = make_uint2(*(unsigned*)&a, *(unsigned*)&b);
  *(uint2*)p = u;
}

// ---------------- layer 0: h = relu(A@s) fp32-gather, hn(fp16), degw -------
__global__ __launch_bounds__(256) void k_spmm_l0(
    const int* __restrict__ ptr, const float2* __restrict__ meta,
    const float4* __restrict__ S4, float* __restrict__ h,
    unsigned short* __restrict__ hn, const float* __restrict__ gn_w,
    const float* __restrict__ gn_b, float* __restrict__ degw) {
  int wid = (blockIdx.x * 256 + threadIdx.x) >> 6;
  int lane = threadIdx.x & 63;
  if (wid >= kN) return;
  int slot = lane >> 4, fc = lane & 15;
  int e0 = __builtin_amdgcn_readfirstlane(ptr[wid]);
  int e1 = __builtin_amdgcn_readfirstlane(ptr[wid + 1]);
  float dsum = 0.f;
  float4 acc = gather_row4<true>(meta, S4, e0, e1, slot, fc, dsum);
  float4 hv = make_float4(fmaxf(acc.x, 0.f), fmaxf(acc.y, 0.f),
                          fmaxf(acc.z, 0.f), fmaxf(acc.w, 0.f));
  float dx = 0.5f * (hv.x - hv.y);
  float rx = dx * rsqrtf(dx * dx + kEPS);
  float dz = 0.5f * (hv.z - hv.w);
  float rz = dz * rsqrtf(dz * dz + kEPS);
  float4 gw = ld4(gn_w + fc * 4);
  float4 gb = ld4(gn_b + fc * 4);
  float4 o = make_float4(rx * gw.x + gb.x, -rx * gw.y + gb.y,
                         rz * gw.z + gb.z, -rz * gw.w + gb.w);
  if (slot == 0) {
    st4(h + wid * 64 + fc * 4, hv);
    st_half4(hn + wid * 64 + fc * 4, o);
    if (fc == 0) degw[wid] = dsum;
  }
}

// ---------------- ODE SpMM: z = A@hn (fp16 gather) ----------------
__global__ __launch_bounds__(256) void k_spmm_ode(
    const int* __restrict__ ptr, const float2* __restrict__ meta,
    const uint2* __restrict__ Sh, float4* __restrict__ z4) {
  int wid = (blockIdx.x * 256 + threadIdx.x) >> 6;
  int lane = threadIdx.x & 63;
  if (wid >= kN) return;
  int slot = lane >> 4, fc = lane & 15;
  int e0 = __builtin_amdgcn_readfirstlane(ptr[wid]);
  int e1 = __builtin_amdgcn_readfirstlane(ptr[wid + 1]);
  float4 acc = gather_row4h(meta, Sh, e0, e1, slot, fc);
  if (slot == 0) z4[wid * 16 + fc] = acc;
}

// ---------------- tiled stage GEMM + RK4 epilogue ----------------
__global__ __launch_bounds__(256) void k_gemm_stage(
    const float* __restrict__ z, const float* __restrict__ W1,
    const float* __restrict__ b1, const float* __restrict__ gn_w,
    const float* __restrict__ gn_b, const float* __restrict__ degw,
    float* __restrict__ h, float* __restrict__ kacc,
    unsigned short* __restrict__ hn, float t_s, float a_next, float coef,
    int init_acc, int is_stage3) {
  constexpr int NT = 128, ST = NT + 4, K = 64;
  __shared__ float Wl[K * 64];
  __shared__ float Zt[K * ST];
  const int tid = threadIdx.x;
  const int base = blockIdx.x * NT;
  const float* Wr = W1 + 64;  // rows 1..64 of W1
  for (int i = tid; i < K * 64; i += 256) Wl[i] = Wr[i];
  for (int idx = tid; idx < (K / 4) * NT; idx += 256) {
    int node = idx & (NT - 1);
    int k4 = idx >> 7;
    int g = base + node;
    float4 v = make_float4(0.f, 0.f, 0.f, 0.f);
    if (g < kN) v = ld4(z + (long)g * 64 + k4 * 4);
    int kk = k4 * 4;
    Zt[(kk + 0) * ST + node] = v.x;
    Zt[(kk + 1) * ST + node] = v.y;
    Zt[(kk + 2) * ST + node] = v.z;
    Zt[(kk + 3) * ST + node] = v.w;
  }
  __syncthreads();
  const int c0 = (tid & 15) * 4;
  const int n0 = (tid >> 4) * 8;
  float acc[8][4] = {};
#pragma unroll 8
  for (int j = 0; j < K; ++j) {
    float4 wv = ld4(Wl + j * 64 + c0);
    float4 za = ld4(Zt + j * ST + n0);
    float4 zb = ld4(Zt + j * ST + n0 + 4);
    float zv[8] = {za.x, za.y, za.z, za.w, zb.x, zb.y, zb.z, zb.w};
#pragma unroll
    for (int i = 0; i < 8; ++i) {
      acc[i][0] += zv[i] * wv.x;
      acc[i][1] += zv[i] * wv.y;
      acc[i][2] += zv[i] * wv.z;
      acc[i][3] += zv[i] * wv.w;
    }
  }
  float4 w0r = ld4(W1 + c0);
  float4 b1v = ld4(b1 + c0);
  float4 bias = make_float4(t_s * w0r.x + b1v.x, t_s * w0r.y + b1v.y,
                            t_s * w0r.z + b1v.z, t_s * w0r.w + b1v.w);
  float4 gw = ld4(gn_w + c0);
  float4 gb = ld4(gn_b + c0);
  const float c6 = kDT / 6.f;
#pragma unroll
  for (int i = 0; i < 8; ++i) {
    int g = base + n0 + i;
    if (g >= kN) break;
    float dg = degw[g];
    float4 kv = make_float4(fmaxf(acc[i][0] + dg * bias.x, 0.f),
                            fmaxf(acc[i][1] + dg * bias.y, 0.f),
                            fmaxf(acc[i][2] + dg * bias.z, 0.f),
                            fmaxf(acc[i][3] + dg * bias.w, 0.f));
    long o64 = (long)g * 64 + c0;
    float4 ka;
    if (init_acc) {
      ka = kv;
    } else {
      ka = ld4(kacc + o64);
      ka.x += coef * kv.x; ka.y += coef * kv.y;
      ka.z += coef * kv.z; ka.w += coef * kv.w;
    }
    if (!is_stage3) st4(kacc + o64, ka);
    float4 hv = ld4(h + o64);
    float4 y;
    if (is_stage3) {
      y = make_float4(hv.x + c6 * ka.x, hv.y + c6 * ka.y,
                      hv.z + c6 * ka.z, hv.w + c6 * ka.w);
      st4(h + o64, y);
    } else {
      y = make_float4(hv.x + a_next * kv.x, hv.y + a_next * kv.y,
                      hv.z + a_next * kv.z, hv.w + a_next * kv.w);
    }
    float dx = 0.5f * (y.x - y.y);
    float rx = dx * rsqrtf(dx * dx + kEPS);
    float dz = 0.5f * (y.z - y.w);
    float rz = dz * rsqrtf(dz * dz + kEPS);
    float4 o = make_float4(rx * gw.x + gb.x, -rx * gw.y + gb.y,
                           rz * gw.z + gb.z, -rz * gw.w + gb.w);
    st_half4(hn + o64, o);
  }
}

// -------- final: fp32 gather over 64-stride padded s2 + log_softmax --------
__global__ __launch_bounds__(256) void k_final(const int* __restrict__ ptr,
                                               const float2* __restrict__ meta,
                                               const float4* __restrict__ s2,
                                               float* __restrict__ out) {
  int wid = (blockIdx.x * 256 + threadIdx.x) >> 6;
  int lane = threadIdx.x & 63;
  if (wid >= kN) return;
  int slot = lane >> 4, fc = lane & 15;
  int e0 = __builtin_amdgcn_readfirstlane(ptr[wid]);
  int e1 = __builtin_amdgcn_readfirstlane(ptr[wid + 1]);
  float dum;
  float4 a = gather_row4<false>(meta, s2, e0, e1, slot, fc, dum);
  bool valid = fc < 10;  // 40 logits = 10 float4 lanes
  float m = valid ? fmaxf(fmaxf(a.x, a.y), fmaxf(a.z, a.w)) : -INFINITY;
#pragma unroll
  for (int off = 1; off < 16; off <<= 1) m = fmaxf(m, __shfl_xor(m, off));
  float s = valid ? expf(a.x - m) + expf(a.y - m) + expf(a.z - m) + expf(a.w - m)
                  : 0.f;
#pragma unroll
  for (int off = 1; off < 16; off <<= 1) s += __shfl_xor(s, off);
  float lse = logf(s) + m;
  if (slot == 0 && valid)
    st4(out + (long)wid * 40 + fc * 4,
        make_float4(a.x - lse, a.y - lse, a.z - lse, a.w - lse));
}

// ------- plain GEMM: out[:, :64@OST] = beta*out + in[:, :64]@W + bias ------
template <int NCOL, int OST>
__global__ __launch_bounds__(256) void k_gemm64(const float* __restrict__ in,
                                                int in_stride,
                                                const float* __restrict__ W,
                                                const float* __restrict__ bias,
                                                float* __restrict__ out, int beta) {
  constexpr int NT = 128, ST = NT + 4, K = 64;
  __shared__ float Wl[K * 64];
  __shared__ float Zt[K * ST];
  const int tid = threadIdx.x;
  const int base = blockIdx.x * NT;
  for (int i = tid; i < K * 64; i += 256) {
    int j = i >> 6, c = i & 63;
    Wl[i] = (c < NCOL) ? W[j * NCOL + c] : 0.f;
  }
  for (int idx = tid; idx < (K / 4) * NT; idx += 256) {
    int node = idx & (NT - 1);
    int k4 = idx >> 7;
    int g = base + node;
    float4 v = make_float4(0.f, 0.f, 0.f, 0.f);
    if (g < kN) v = ld4(in + (long)g * in_stride + k4 * 4);
    int kk = k4 * 4;
    Zt[(kk + 0) * ST + node] = v.x;
    Zt[(kk + 1) * ST + node] = v.y;
    Zt[(kk + 2) * ST + node] = v.z;
    Zt[(kk + 3) * ST + node] = v.w;
  }
  __syncthreads();
  const int c0 = (tid & 15) * 4;
  const int n0 = (tid >> 4) * 8;
  float acc[8][4] = {};
#pragma unroll 8
  for (int j = 0; j < K; ++j) {
    float4 wv = ld4(Wl + j * 64 + c0);
    float4 za = ld4(Zt + j * ST + n0);
    float4 zb = ld4(Zt + j * ST + n0 + 4);
    float zv[8] = {za.x, za.y, za.z, za.w, zb.x, zb.y, zb.z, zb.w};
#pragma unroll
    for (int i = 0; i < 8; ++i) {
      acc[i][0] += zv[i] * wv.x;
      acc[i][1] += zv[i] * wv.y;
      acc[i][2] += zv[i] * wv.z;
      acc[i][3] += zv[i] * wv.w;
    }
  }
  float4 bv = make_float4(0.f, 0.f, 0.f, 0.f);
  if (bias && c0 < NCOL) bv = ld4(bias + c0);
#pragma unroll
  for (int i = 0; i < 8; ++i) {
    int g = base + n0 + i;
    if (g >= kN) break;
    float* op = out + (long)g * OST + c0;
    float4 o = make_float4(acc[i][0] + bv.x, acc[i][1] + bv.y,
                           acc[i][2] + bv.z, acc[i][3] + bv.w);
    if (beta) {
      float4 p = ld4(op);
      o.x += p.x; o.y += p.y; o.z += p.z; o.w += p.w;
    }
    st4(op, o);
  }
}

// ---------------- launch ----------------
extern "C" void kernel_launch(void* const* d_in, const int* in_sizes, int n_in,
                              void* d_out, int out_size, void* d_ws, size_t ws_size,
                              hipStream_t stream) {
  const float* x = (const float*)d_in[0];
  const int* src = (const int*)d_in[1];
  const int* tgt = (const int*)d_in[2];
  const float* mw = (const float*)d_in[3];
  const float* W0 = (const float*)d_in[4];
  const float* b0 = (const float*)d_in[5];
  const float* gnw = (const float*)d_in[6];
  const float* gnb = (const float*)d_in[7];
  const float* W1 = (const float*)d_in[8];
  const float* b1 = (const float*)d_in[9];
  const float* W2 = (const float*)d_in[10];
  const float* b2 = (const float*)d_in[11];
  float* out = (float*)d_out;

  // workspace carve-up (16B aligned regions)
  int* cnt_run = (int*)d_ws;                  // kNPAD ints
  int* csr_ptr = cnt_run + kNPAD;             // kNPAD ints (need kN+1)
  int* bsum = csr_ptr + kNPAD;                // 128 ints
  float2* meta = (float2*)(bsum + 128);       // kE float2
  float* degw = (float*)(meta + kE);          // kNPAD floats (also meta OOB pad)
  float* h = degw + kNPAD;                    // kN*64 f32
  unsigned short* hn = (unsigned short*)(h + (long)kN * 64);  // kN*64 f16
  float* z = (float*)(hn + (long)kN * 64);    // kN*64 f32
  float* kacc = z + (long)kN * 64;            // kN*64 f32

  // CSR build
  k_zero<<<391, 256, 0, stream>>>(cnt_run);
  k_hist<<<6250, 256, 0, stream>>>(tgt, cnt_run);
  k_scan_a<<<98, 256, 0, stream>>>(cnt_run, csr_ptr, bsum);
  k_scan_b<<<1, 64, 0, stream>>>(bsum, 98);
  k_scan_c<<<391, 256, 0, stream>>>(bsum, csr_ptr, cnt_run);
  k_scatter<<<6250, 256, 0, stream>>>(src, tgt, mw, cnt_run, meta);

  // layer 0: z = x@W0 + b0 (two K=64 passes), then h(f32)/hn(f16)/degw
  k_gemm64<64, 64><<<782, 256, 0, stream>>>(x, 128, W0, nullptr, z, 0);
  k_gemm64<64, 64><<<782, 256, 0, stream>>>(x + 64, 128, W0 + 64 * 64, b0, z, 1);
  k_spmm_l0<<<25000, 256, 0, stream>>>(csr_ptr, meta, (const float4*)z, h, hn,
                                       gnw, gnb, degw);

  // RK4 over t = 0, .25, .5, .75
  for (int step = 0; step < 4; ++step) {
    float t = step * kDT;
    const float ts[4] = {t, t + 0.5f * kDT, t + 0.5f * kDT, t + kDT};
    const float an[4] = {0.5f * kDT, 0.5f * kDT, kDT, 0.f};
    const float cf[4] = {1.f, 2.f, 2.f, 1.f};
    for (int s = 0; s < 4; ++s) {
      k_spmm_ode<<<25000, 256, 0, stream>>>(csr_ptr, meta, (const uint2*)hn,
                                            (float4*)z);
      k_gemm_stage<<<782, 256, 0, stream>>>(z, W1, b1, gnw, gnb, degw, h, kacc,
                                            hn, ts[s], an[s], cf[s],
                                            (s == 0) ? 1 : 0, (s == 3) ? 1 : 0);
    }
  }

  // final layer: s2 = h@W2 + b2 into 64-stride padded buffer (cols>=40 zero)
  k_gemm64<40, 64><<<782, 256, 0, stream>>>(h, 64, W2, b2, z, 0);
  k_final<<<25000, 256, 0, stream>>>(csr_ptr, meta, (const float4*)z, out);
}

// Round 6
// 1483.528 us; speedup vs baseline: 1.3800x; 1.2339x over previous
//
#include <hip/hip_runtime.h>
#include <hip/hip_fp16.h>
#include <math.h>

// GraphODE (GCN + RK4 ODE block) on MI355X.
// Round 6: lean fusion of SpMM + stage GEMM + RK4 epilogue in ONE kernel:
//  - per wave: 4 nodes gathered SERIALLY (one-node register footprint;
//    round-2's 8-node register batching caused VGPR=256 spills),
//  - reduced z parked in per-wave LDS (4KB/block), then a 4-node batched
//    GEMM vs LDS-resident W1 (acc = 16 VGPR, W reads amortized 4x),
//  - epilogue: slot s owns node base+s -> all 64 lanes active, coalesced.
//  - hn is fp16 and DOUBLE-BUFFERED (A/B) since reads/writes now overlap.
// Final layer similarly fused: gather(A@h) + W2 + log_softmax (s2/gemm40 gone).

constexpr int kN = 100000;   // nodes
constexpr int kE = 1600000;  // edges
constexpr int kNPAD = 100352; // 98*1024
constexpr float kDT = 0.25f;
constexpr float kEPS = 1e-5f;

__device__ __forceinline__ float4 ld4(const float* p) { return *(const float4*)p; }
__device__ __forceinline__ void st4(float* p, float4 v) { *(float4*)p = v; }

// ---------------- CSR build ----------------
__global__ void k_zero(int* cnt) {
  int i = blockIdx.x * 256 + threadIdx.x;
  if (i < kN) cnt[i] = 0;
}

__global__ void k_hist(const int* __restrict__ tgt, int* __restrict__ cnt) {
  int e = blockIdx.x * 256 + threadIdx.x;
  if (e < kE) atomicAdd(&cnt[tgt[e]], 1);
}

__global__ __launch_bounds__(256) void k_scan_a(const int* __restrict__ cnt,
                                                int* __restrict__ ptr,
                                                int* __restrict__ bsum) {
  int tid = threadIdx.x;
  int base = blockIdx.x * 1024;
  int i0 = base + tid * 4;
  int v[4];
#pragma unroll
  for (int t = 0; t < 4; ++t) v[t] = (i0 + t < kN) ? cnt[i0 + t] : 0;
  int ts = v[0] + v[1] + v[2] + v[3];
  int lane = tid & 63;
  int x = ts;
#pragma unroll
  for (int off = 1; off < 64; off <<= 1) {
    int y = __shfl_up(x, off);
    if (lane >= off) x += y;
  }
  __shared__ int wsum[4];
  if (lane == 63) wsum[tid >> 6] = x;
  __syncthreads();
  int woff = 0;
#pragma unroll
  for (int w = 0; w < 4; ++w)
    if (w < (tid >> 6)) woff += wsum[w];
  int o = woff + (x - ts);  // exclusive within block
#pragma unroll
  for (int t = 0; t < 4; ++t) {
    if (i0 + t < kN) ptr[i0 + t] = o;
    o += v[t];
  }
  if (tid == 255) bsum[blockIdx.x] = woff + x;  // block total
}

__global__ void k_scan_b(int* bsum, int nb) {
  int lane = threadIdx.x;  // blockDim = 64
  int carry = 0;
  for (int b = 0; b < nb; b += 64) {
    int i = b + lane;
    int v = (i < nb) ? bsum[i] : 0;
    int x = v;
#pragma unroll
    for (int off = 1; off < 64; off <<= 1) {
      int y = __shfl_up(x, off);
      if (lane >= off) x += y;
    }
    if (i < nb) bsum[i] = carry + x - v;  // exclusive
    carry += __shfl(x, 63);
  }
}

__global__ void k_scan_c(const int* __restrict__ bsum, int* __restrict__ ptr,
                         int* __restrict__ runp) {
  int i = blockIdx.x * 256 + threadIdx.x;
  if (i < kN) {
    int v = ptr[i] + bsum[i >> 10];
    ptr[i] = v;
    runp[i] = v;
  }
  if (i == 0) ptr[kN] = kE;
}

__global__ void k_scatter(const int* __restrict__ src, const int* __restrict__ tgt,
                          const float* __restrict__ w, int* __restrict__ runp,
                          float2* __restrict__ meta) {
  int e = blockIdx.x * 256 + threadIdx.x;
  if (e < kE) {
    int t = tgt[e];
    int pos = atomicAdd(&runp[t], 1);
    meta[pos] = make_float2(__int_as_float(src[e]), w[e]);
  }
}

// ---------------- fp32 float4 gather: 4 edges per VMEM instruction ---------
template <bool DSUM>
__device__ __forceinline__ void g_chunk4(const float2* __restrict__ meta,
                                         const float4* __restrict__ S4,
                                         int e, int rem, int slot, int fc,
                                         float4& acc, float& ds) {
  float2 m0 = meta[e + 0], m1 = meta[e + 1], m2 = meta[e + 2], m3 = meta[e + 3];
  int idx = slot == 1 ? __float_as_int(m1.x)
          : slot == 2 ? __float_as_int(m2.x)
          : slot == 3 ? __float_as_int(m3.x)
                      : __float_as_int(m0.x);
  float w = slot == 1 ? m1.y : slot == 2 ? m2.y : slot == 3 ? m3.y : m0.y;
  if (rem < 4) {
    bool ok = slot < rem;
    idx = ok ? idx : 0;
    w = ok ? w : 0.f;
  }
  float4 v = S4[idx * 16 + fc];
  acc.x += w * v.x; acc.y += w * v.y; acc.z += w * v.z; acc.w += w * v.w;
  if (DSUM) ds += w;
}

template <bool DSUM>
__device__ __forceinline__ float4 gather_row4(const float2* __restrict__ meta,
                                              const float4* __restrict__ S4,
                                              int e0, int e1, int slot, int fc,
                                              float& dsum) {
  float4 acc = make_float4(0.f, 0.f, 0.f, 0.f);
  float ds = 0.f;
  int e = e0;
  for (; e + 16 <= e1; e += 16) {
    g_chunk4<DSUM>(meta, S4, e + 0, 4, slot, fc, acc, ds);
    g_chunk4<DSUM>(meta, S4, e + 4, 4, slot, fc, acc, ds);
    g_chunk4<DSUM>(meta, S4, e + 8, 4, slot, fc, acc, ds);
    g_chunk4<DSUM>(meta, S4, e + 12, 4, slot, fc, acc, ds);
  }
  if (e + 8 <= e1) {
    g_chunk4<DSUM>(meta, S4, e + 0, 4, slot, fc, acc, ds);
    g_chunk4<DSUM>(meta, S4, e + 4, 4, slot, fc, acc, ds);
    e += 8;
  }
  if (e + 4 <= e1) {
    g_chunk4<DSUM>(meta, S4, e, 4, slot, fc, acc, ds);
    e += 4;
  }
  if (e < e1) g_chunk4<DSUM>(meta, S4, e, e1 - e, slot, fc, acc, ds);
  acc.x += __shfl_xor(acc.x, 16); acc.y += __shfl_xor(acc.y, 16);
  acc.z += __shfl_xor(acc.z, 16); acc.w += __shfl_xor(acc.w, 16);
  acc.x += __shfl_xor(acc.x, 32); acc.y += __shfl_xor(acc.y, 32);
  acc.z += __shfl_xor(acc.z, 32); acc.w += __shfl_xor(acc.w, 32);
  if (DSUM) {
    ds += __shfl_xor(ds, 16);
    ds += __shfl_xor(ds, 32);
    dsum = ds;
  }
  return acc;
}

// ---------------- fp16 gather: 4 edges/instr, 8B/lane ----------------------
__device__ __forceinline__ void g_chunk4h(const float2* __restrict__ meta,
                                          const uint2* __restrict__ Sh,
                                          int e, int rem, int slot, int fc,
                                          float4& acc) {
  float2 m0 = meta[e + 0], m1 = meta[e + 1], m2 = meta[e + 2], m3 = meta[e + 3];
  int idx = slot == 1 ? __float_as_int(m1.x)
          : slot == 2 ? __float_as_int(m2.x)
          : slot == 3 ? __float_as_int(m3.x)
                      : __float_as_int(m0.x);
  float w = slot == 1 ? m1.y : slot == 2 ? m2.y : slot == 3 ? m3.y : m0.y;
  if (rem < 4) {
    bool ok = slot < rem;
    idx = ok ? idx : 0;
    w = ok ? w : 0.f;
  }
  uint2 u = Sh[idx * 16 + fc];  // 4 halfs
  float2 f01 = __half22float2(*(const __half2*)&u.x);
  float2 f23 = __half22float2(*(const __half2*)&u.y);
  acc.x += w * f01.x; acc.y += w * f01.y;
  acc.z += w * f23.x; acc.w += w * f23.y;
}

__device__ __forceinline__ float4 gather_row4h(const float2* __restrict__ meta,
                                               const uint2* __restrict__ Sh,
                                               int e0, int e1, int slot, int fc) {
  float4 acc = make_float4(0.f, 0.f, 0.f, 0.f);
  int e = e0;
  for (; e + 16 <= e1; e += 16) {
    g_chunk4h(meta, Sh, e + 0, 4, slot, fc, acc);
    g_chunk4h(meta, Sh, e + 4, 4, slot, fc, acc);
    g_chunk4h(meta, Sh, e + 8, 4, slot, fc, acc);
    g_chunk4h(meta, Sh, e + 12, 4, slot, fc, acc);
  }
  if (e + 8 <= e1) {
    g_chunk4h(meta, Sh, e + 0, 4, slot, fc, acc);
    g_chunk4h(meta, Sh, e + 4, 4, slot, fc, acc);
    e += 8;
  }
  if (e + 4 <= e1) {
    g_chunk4h(meta, Sh, e, 4, slot, fc, acc);
    e += 4;
  }
  if (e < e1) g_chunk4h(meta, Sh, e, e1 - e, slot, fc, acc);
  acc.x += __shfl_xor(acc.x, 16); acc.y += __shfl_xor(acc.y, 16);
  acc.z += __shfl_xor(acc.z, 16); acc.w += __shfl_xor(acc.w, 16);
  acc.x += __shfl_xor(acc.x, 32); acc.y += __shfl_xor(acc.y, 32);
  acc.z += __shfl_xor(acc.z, 32); acc.w += __shfl_xor(acc.w, 32);
  return acc;
}

__device__ __forceinline__ void st_half4(unsigned short* p, float4 v) {
  __half2 a = __floats2half2_rn(v.x, v.y);
  __half2 b = __floats2half2_rn(v.z, v.w);
  uint2 u = make_uint2(*(unsigned*)&a, *(unsigned*)&b);
  *(uint2*)p = u;
}

// ---------------- layer 0: h = relu(A@s) fp32-gather, hn(fp16), degw -------
__global__ __launch_bounds__(256) void k_spmm_l0(
    const int* __restrict__ ptr, const float2* __restrict__ meta,
    const float4* __restrict__ S4, float* __restrict__ h,
    unsigned short* __restrict__ hn, const float* __restrict__ gn_w,
    const float* __restrict__ gn_b, float* __restrict__ degw) {
  int wid = (blockIdx.x * 256 + threadIdx.x) >> 6;
  int lane = threadIdx.x & 63;
  if (wid >= kN) return;
  int slot = lane >> 4, fc = lane & 15;
  int e0 = __builtin_amdgcn_readfirstlane(ptr[wid]);
  int e1 = __builtin_amdgcn_readfirstlane(ptr[wid + 1]);
  float dsum = 0.f;
  float4 acc = gather_row4<true>(meta, S4, e0, e1, slot, fc, dsum);
  float4 hv = make_float4(fmaxf(acc.x, 0.f), fmaxf(acc.y, 0.f),
                          fmaxf(acc.z, 0.f), fmaxf(acc.w, 0.f));
  float dx = 0.5f * (hv.x - hv.y);
  float rx = dx * rsqrtf(dx * dx + kEPS);
  float dz = 0.5f * (hv.z - hv.w);
  float rz = dz * rsqrtf(dz * dz + kEPS);
  float4 gw = ld4(gn_w + fc * 4);
  float4 gb = ld4(gn_b + fc * 4);
  float4 o = make_float4(rx * gw.x + gb.x, -rx * gw.y + gb.y,
                         rz * gw.z + gb.z, -rz * gw.w + gb.w);
  if (slot == 0) {
    st4(h + wid * 64 + fc * 4, hv);
    st_half4(hn + wid * 64 + fc * 4, o);
    if (fc == 0) degw[wid] = dsum;
  }
}

// -------- fused ODE stage: gather(A@hn) + W1-GEMM + RK4 epilogue -----------
// 4 nodes per wave: gather serially (lean regs) -> z staged in per-wave LDS
// -> 4-node batched GEMM vs LDS W1 -> butterfly over slots -> epilogue with
// slot s owning node base+s (all 64 lanes active, coalesced 1KB stores).
template <int INIT, int IS3>
__global__ __launch_bounds__(256) void k_stage_fused(
    const int* __restrict__ ptr, const float2* __restrict__ meta,
    const uint2* __restrict__ hn_in, const float* __restrict__ W1,
    const float* __restrict__ b1, const float* __restrict__ gn_w,
    const float* __restrict__ gn_b, const float* __restrict__ degw,
    float* __restrict__ h, float* __restrict__ kacc,
    unsigned short* __restrict__ hn_out, float t_s, float a_next, float coef) {
  __shared__ float Wl[64 * 64];     // W1 rows 1..64
  __shared__ float zsh[4][4 * 64];  // per-wave z staging (4 nodes x 64)
  const int tid = threadIdx.x;
  for (int i = tid * 4; i < 4096; i += 1024) *(float4*)&Wl[i] = ld4(W1 + 64 + i);
  __syncthreads();
  const int wave = tid >> 6, lane = tid & 63;
  const int slot = lane >> 4, fc = lane & 15;
  const int c0 = fc * 4;
  const int base = (blockIdx.x * 4 + wave) * 4;

  // per-lane column constants
  float4 w0r = ld4(W1 + c0);
  float4 b1v = ld4(b1 + c0);
  float4 bias = make_float4(t_s * w0r.x + b1v.x, t_s * w0r.y + b1v.y,
                            t_s * w0r.z + b1v.z, t_s * w0r.w + b1v.w);
  float4 gw = ld4(gn_w + c0);
  float4 gb = ld4(gn_b + c0);

  // Phase B: serial gathers, park z in LDS
#pragma unroll
  for (int u = 0; u < 4; ++u) {
    int n = base + u;
    int e0 = __builtin_amdgcn_readfirstlane(ptr[n]);
    int e1 = __builtin_amdgcn_readfirstlane(ptr[n + 1]);
    float4 a = gather_row4h(meta, hn_in, e0, e1, slot, fc);
    if (slot == 0) st4(&zsh[wave][u * 64 + c0], a);
  }

  // Phase C: batched GEMM, slot s covers j in [16s, 16s+16)
  float4 a0 = make_float4(0, 0, 0, 0), a1 = a0, a2 = a0, a3 = a0;
#pragma unroll
  for (int t = 0; t < 16; ++t) {
    int j = slot * 16 + t;
    float4 w4 = ld4(&Wl[j * 64 + c0]);
    float z0 = zsh[wave][0 * 64 + j];
    float z1 = zsh[wave][1 * 64 + j];
    float z2 = zsh[wave][2 * 64 + j];
    float z3 = zsh[wave][3 * 64 + j];
    a0.x += z0 * w4.x; a0.y += z0 * w4.y; a0.z += z0 * w4.z; a0.w += z0 * w4.w;
    a1.x += z1 * w4.x; a1.y += z1 * w4.y; a1.z += z1 * w4.z; a1.w += z1 * w4.w;
    a2.x += z2 * w4.x; a2.y += z2 * w4.y; a2.z += z2 * w4.z; a2.w += z2 * w4.w;
    a3.x += z3 * w4.x; a3.y += z3 * w4.y; a3.z += z3 * w4.z; a3.w += z3 * w4.w;
  }
  // butterfly over slots -> every lane holds full sums for its 4 cols
#pragma unroll
  for (int off = 16; off <= 32; off <<= 1) {
    a0.x += __shfl_xor(a0.x, off); a0.y += __shfl_xor(a0.y, off);
    a0.z += __shfl_xor(a0.z, off); a0.w += __shfl_xor(a0.w, off);
    a1.x += __shfl_xor(a1.x, off); a1.y += __shfl_xor(a1.y, off);
    a1.z += __shfl_xor(a1.z, off); a1.w += __shfl_xor(a1.w, off);
    a2.x += __shfl_xor(a2.x, off); a2.y += __shfl_xor(a2.y, off);
    a2.z += __shfl_xor(a2.z, off); a2.w += __shfl_xor(a2.w, off);
    a3.x += __shfl_xor(a3.x, off); a3.y += __shfl_xor(a3.y, off);
    a3.z += __shfl_xor(a3.z, off); a3.w += __shfl_xor(a3.w, off);
  }

  // Phase D: epilogue, slot s owns node base+s
  const int n = base + slot;
  float4 accs;
  accs.x = slot == 0 ? a0.x : slot == 1 ? a1.x : slot == 2 ? a2.x : a3.x;
  accs.y = slot == 0 ? a0.y : slot == 1 ? a1.y : slot == 2 ? a2.y : a3.y;
  accs.z = slot == 0 ? a0.z : slot == 1 ? a1.z : slot == 2 ? a2.z : a3.z;
  accs.w = slot == 0 ? a0.w : slot == 1 ? a1.w : slot == 2 ? a2.w : a3.w;
  float dg = degw[n];
  float4 kv = make_float4(fmaxf(accs.x + dg * bias.x, 0.f),
                          fmaxf(accs.y + dg * bias.y, 0.f),
                          fmaxf(accs.z + dg * bias.z, 0.f),
                          fmaxf(accs.w + dg * bias.w, 0.f));
  long o = (long)n * 64 + c0;
  float4 ka;
  if (INIT) {
    ka = kv;
  } else {
    ka = ld4(kacc + o);
    ka.x += coef * kv.x; ka.y += coef * kv.y;
    ka.z += coef * kv.z; ka.w += coef * kv.w;
  }
  if (!IS3) st4(kacc + o, ka);
  float4 hv = ld4(h + o);
  float4 y;
  if (IS3) {
    const float c6 = kDT / 6.f;
    y = make_float4(hv.x + c6 * ka.x, hv.y + c6 * ka.y,
                    hv.z + c6 * ka.z, hv.w + c6 * ka.w);
    st4(h + o, y);
  } else {
    y = make_float4(hv.x + a_next * kv.x, hv.y + a_next * kv.y,
                    hv.z + a_next * kv.z, hv.w + a_next * kv.w);
  }
  float dx = 0.5f * (y.x - y.y);
  float rx = dx * rsqrtf(dx * dx + kEPS);
  float dz = 0.5f * (y.z - y.w);
  float rz = dz * rsqrtf(dz * dz + kEPS);
  float4 on = make_float4(rx * gw.x + gb.x, -rx * gw.y + gb.y,
                          rz * gw.z + gb.z, -rz * gw.w + gb.w);
  st_half4(hn_out + o, on);
}

// ------ fused final: gather(A@h) + W2-GEMM + degw*b2 + log_softmax ---------
__global__ __launch_bounds__(256) void k_fin2(
    const int* __restrict__ ptr, const float2* __restrict__ meta,
    const float4* __restrict__ h4, const float* __restrict__ W2,
    const float* __restrict__ b2, const float* __restrict__ degw,
    float* __restrict__ out) {
  __shared__ float Wl[64 * 40];
  __shared__ float zsh[4][4 * 64];
  const int tid = threadIdx.x;
  for (int i = tid; i < 2560; i += 256) Wl[i] = W2[i];
  __syncthreads();
  const int wave = tid >> 6, lane = tid & 63;
  const int slot = lane >> 4, fc = lane & 15;
  const int c0 = fc * 4;
  const bool valid = fc < 10;
  const int base = (blockIdx.x * 4 + wave) * 4;
  float dum;
#pragma unroll
  for (int u = 0; u < 4; ++u) {
    int n = base + u;
    int e0 = __builtin_amdgcn_readfirstlane(ptr[n]);
    int e1 = __builtin_amdgcn_readfirstlane(ptr[n + 1]);
    float4 a = gather_row4<false>(meta, h4, e0, e1, slot, fc, dum);
    if (slot == 0) st4(&zsh[wave][u * 64 + c0], a);
  }
  float4 a0 = make_float4(0, 0, 0, 0), a1 = a0, a2 = a0, a3 = a0;
#pragma unroll
  for (int t = 0; t < 16; ++t) {
    int j = slot * 16 + t;
    float4 w4 = valid ? ld4(&Wl[j * 40 + c0]) : make_float4(0, 0, 0, 0);
    float z0 = zsh[wave][0 * 64 + j];
    float z1 = zsh[wave][1 * 64 + j];
    float z2 = zsh[wave][2 * 64 + j];
    float z3 = zsh[wave][3 * 64 + j];
    a0.x += z0 * w4.x; a0.y += z0 * w4.y; a0.z += z0 * w4.z; a0.w += z0 * w4.w;
    a1.x += z1 * w4.x; a1.y += z1 * w4.y; a1.z += z1 * w4.z; a1.w += z1 * w4.w;
    a2.x += z2 * w4.x; a2.y += z2 * w4.y; a2.z += z2 * w4.z; a2.w += z2 * w4.w;
    a3.x += z3 * w4.x; a3.y += z3 * w4.y; a3.z += z3 * w4.z; a3.w += z3 * w4.w;
  }
#pragma unroll
  for (int off = 16; off <= 32; off <<= 1) {
    a0.x += __shfl_xor(a0.x, off); a0.y += __shfl_xor(a0.y, off);
    a0.z += __shfl_xor(a0.z, off); a0.w += __shfl_xor(a0.w, off);
    a1.x += __shfl_xor(a1.x, off); a1.y += __shfl_xor(a1.y, off);
    a1.z += __shfl_xor(a1.z, off); a1.w += __shfl_xor(a1.w, off);
    a2.x += __shfl_xor(a2.x, off); a2.y += __shfl_xor(a2.y, off);
    a2.z += __shfl_xor(a2.z, off); a2.w += __shfl_xor(a2.w, off);
    a3.x += __shfl_xor(a3.x, off); a3.y += __shfl_xor(a3.y, off);
    a3.z += __shfl_xor(a3.z, off); a3.w += __shfl_xor(a3.w, off);
  }
  const int n = base + slot;
  float4 a;
  a.x = slot == 0 ? a0.x : slot == 1 ? a1.x : slot == 2 ? a2.x : a3.x;
  a.y = slot == 0 ? a0.y : slot == 1 ? a1.y : slot == 2 ? a2.y : a3.y;
  a.z = slot == 0 ? a0.z : slot == 1 ? a1.z : slot == 2 ? a2.z : a3.z;
  a.w = slot == 0 ? a0.w : slot == 1 ? a1.w : slot == 2 ? a2.w : a3.w;
  float dg = degw[n];
  float4 b2v = valid ? ld4(b2 + c0) : make_float4(0, 0, 0, 0);
  a.x += dg * b2v.x; a.y += dg * b2v.y; a.z += dg * b2v.z; a.w += dg * b2v.w;
  float m = valid ? fmaxf(fmaxf(a.x, a.y), fmaxf(a.z, a.w)) : -INFINITY;
#pragma unroll
  for (int off = 1; off < 16; off <<= 1) m = fmaxf(m, __shfl_xor(m, off));
  float s = valid ? expf(a.x - m) + expf(a.y - m) + expf(a.z - m) + expf(a.w - m)
                  : 0.f;
#pragma unroll
  for (int off = 1; off < 16; off <<= 1) s += __shfl_xor(s, off);
  float lse = logf(s) + m;
  if (valid)
    st4(out + (long)n * 40 + c0,
        make_float4(a.x - lse, a.y - lse, a.z - lse, a.w - lse));
}

// ------- plain GEMM (layer-0 input transform): out = in@W + bias -----------
template <int NCOL, int OST>
__global__ __launch_bounds__(256) void k_gemm64(const float* __restrict__ in,
                                                int in_stride,
                                                const float* __restrict__ W,
                                                const float* __restrict__ bias,
                                                float* __restrict__ out, int beta) {
  constexpr int NT = 128, ST = NT + 4, K = 64;
  __shared__ float Wl[K * 64];
  __shared__ float Zt[K * ST];
  const int tid = threadIdx.x;
  const int base = blockIdx.x * NT;
  for (int i = tid; i < K * 64; i += 256) {
    int j = i >> 6, c = i & 63;
    Wl[i] = (c < NCOL) ? W[j * NCOL + c] : 0.f;
  }
  for (int idx = tid; idx < (K / 4) * NT; idx += 256) {
    int node = idx & (NT - 1);
    int k4 = idx >> 7;
    int g = base + node;
    float4 v = make_float4(0.f, 0.f, 0.f, 0.f);
    if (g < kN) v = ld4(in + (long)g * in_stride + k4 * 4);
    int kk = k4 * 4;
    Zt[(kk + 0) * ST + node] = v.x;
    Zt[(kk + 1) * ST + node] = v.y;
    Zt[(kk + 2) * ST + node] = v.z;
    Zt[(kk + 3) * ST + node] = v.w;
  }
  __syncthreads();
  const int c0 = (tid & 15) * 4;
  const int n0 = (tid >> 4) * 8;
  float acc[8][4] = {};
#pragma unroll 8
  for (int j = 0; j < K; ++j) {
    float4 wv = ld4(Wl + j * 64 + c0);
    float4 za = ld4(Zt + j * ST + n0);
    float4 zb = ld4(Zt + j * ST + n0 + 4);
    float zv[8] = {za.x, za.y, za.z, za.w, zb.x, zb.y, zb.z, zb.w};
#pragma unroll
    for (int i = 0; i < 8; ++i) {
      acc[i][0] += zv[i] * wv.x;
      acc[i][1] += zv[i] * wv.y;
      acc[i][2] += zv[i] * wv.z;
      acc[i][3] += zv[i] * wv.w;
    }
  }
  float4 bv = make_float4(0.f, 0.f, 0.f, 0.f);
  if (bias && c0 < NCOL) bv = ld4(bias + c0);
#pragma unroll
  for (int i = 0; i < 8; ++i) {
    int g = base + n0 + i;
    if (g >= kN) break;
    float* op = out + (long)g * OST + c0;
    float4 o = make_float4(acc[i][0] + bv.x, acc[i][1] + bv.y,
                           acc[i][2] + bv.z, acc[i][3] + bv.w);
    if (beta) {
      float4 p = ld4(op);
      o.x += p.x; o.y += p.y; o.z += p.z; o.w += p.w;
    }
    st4(op, o);
  }
}

// ---------------- launch ----------------
extern "C" void kernel_launch(void* const* d_in, const int* in_sizes, int n_in,
                              void* d_out, int out_size, void* d_ws, size_t ws_size,
                              hipStream_t stream) {
  const float* x = (const float*)d_in[0];
  const int* src = (const int*)d_in[1];
  const int* tgt = (const int*)d_in[2];
  const float* mw = (const float*)d_in[3];
  const float* W0 = (const float*)d_in[4];
  const float* b0 = (const float*)d_in[5];
  const float* gnw = (const float*)d_in[6];
  const float* gnb = (const float*)d_in[7];
  const float* W1 = (const float*)d_in[8];
  const float* b1 = (const float*)d_in[9];
  const float* W2 = (const float*)d_in[10];
  const float* b2 = (const float*)d_in[11];
  float* out = (float*)d_out;

  // workspace carve-up (16B aligned regions)
  int* cnt_run = (int*)d_ws;                  // kNPAD ints
  int* csr_ptr = cnt_run + kNPAD;             // kNPAD ints (need kN+1)
  int* bsum = csr_ptr + kNPAD;                // 128 ints
  float2* meta = (float2*)(bsum + 128);       // kE float2
  float* degw = (float*)(meta + kE);          // kNPAD floats (also meta OOB pad)
  float* h = degw + kNPAD;                    // kN*64 f32
  unsigned short* hnA = (unsigned short*)(h + (long)kN * 64);  // kN*64 f16
  unsigned short* hnB = hnA + (long)kN * 64;                   // kN*64 f16
  float* z = (float*)(hnB + (long)kN * 64);   // kN*64 f32 (layer-0 staging)
  float* kacc = z + (long)kN * 64;            // kN*64 f32

  // CSR build
  k_zero<<<391, 256, 0, stream>>>(cnt_run);
  k_hist<<<6250, 256, 0, stream>>>(tgt, cnt_run);
  k_scan_a<<<98, 256, 0, stream>>>(cnt_run, csr_ptr, bsum);
  k_scan_b<<<1, 64, 0, stream>>>(bsum, 98);
  k_scan_c<<<391, 256, 0, stream>>>(bsum, csr_ptr, cnt_run);
  k_scatter<<<6250, 256, 0, stream>>>(src, tgt, mw, cnt_run, meta);

  // layer 0: z = x@W0 + b0 (two K=64 passes), then h(f32)/hnA(f16)/degw
  k_gemm64<64, 64><<<782, 256, 0, stream>>>(x, 128, W0, nullptr, z, 0);
  k_gemm64<64, 64><<<782, 256, 0, stream>>>(x + 64, 128, W0 + 64 * 64, b0, z, 1);
  k_spmm_l0<<<25000, 256, 0, stream>>>(csr_ptr, meta, (const float4*)z, h, hnA,
                                       gnw, gnb, degw);

  // RK4 over t = 0, .25, .5, .75 ; hn ping-pongs A->B->A->B->A per step
  for (int step = 0; step < 4; ++step) {
    float t = step * kDT;
    k_stage_fused<1, 0><<<6250, 256, 0, stream>>>(
        csr_ptr, meta, (const uint2*)hnA, W1, b1, gnw, gnb, degw, h, kacc, hnB,
        t, 0.5f * kDT, 1.f);
    k_stage_fused<0, 0><<<6250, 256, 0, stream>>>(
        csr_ptr, meta, (const uint2*)hnB, W1, b1, gnw, gnb, degw, h, kacc, hnA,
        t + 0.5f * kDT, 0.5f * kDT, 2.f);
    k_stage_fused<0, 0><<<6250, 256, 0, stream>>>(
        csr_ptr, meta, (const uint2*)hnA, W1, b1, gnw, gnb, degw, h, kacc, hnB,
        t + 0.5f * kDT, kDT, 2.f);
    k_stage_fused<0, 1><<<6250, 256, 0, stream>>>(
        csr_ptr, meta, (const uint2*)hnB, W1, b1, gnw, gnb, degw, h, kacc, hnA,
        t + kDT, 0.f, 1.f);
  }

  // fused final layer: out = log_softmax((A@h)@W2 + degw*b2)
  k_fin2<<<6250, 256, 0, stream>>>(csr_ptr, meta, (const float4*)h, W2, b2,
                                   degw, out);
}